// Round 1
// baseline (178.858 us; speedup 1.0000x reference)
//
#include <hip/hip_runtime.h>
#include <hip/hip_fp16.h>

// B=32768, D=128, L=3, R=64, O=64. fp32 in/out, f16 MFMA compute.
// Wave split: p = d-parity, kh = r-half (K-split), sb = s-half.
// Each wave M-unrolls over both 32-row m-blocks -> core chunk LDS reads are
// read-once (was read-twice), 32 KB chunks double-buffered (32 barriers/stage).
typedef _Float16 f16x8 __attribute__((ext_vector_type(8)));
typedef float f32x16 __attribute__((ext_vector_type(16)));

union H2x4 { f16x8 v; __half2 h2[4]; unsigned u[4]; };
union U1H2 { unsigned u; __half2 h; };

#define TB 64               // batch rows per workgroup (512 WGs = 2/CU)
// LDS layout (bytes)
#define DBUF_OFF 0          // 2 x 32KB core chunk double buffer (+ reduce scratch)
#define T_OFF    65536      // T buffer [64][64]f16, 128B rows, XOR swz = 8192B
#define XN_OFF   65536      // xn half-slice ALIASES T: [dl<64][row<64] pitch 136B
#define SMEM_BYTES 74240    // 2 WGs/CU (148480 <= 160K)
// workspace layout (bytes)
#define WS_CT1   0          // core1 -> [d][s][r] f16, swizzled, 1MB
#define WS_CT2   1048576    // core2 same
#define WS_L0T   2097152    // layer0^T [r][d] f16, 16KB
#define WS_LASTT 2113536    // last^T [o][r] f16, 8KB

#define WAITBAR0() asm volatile("s_waitcnt vmcnt(0)\n\ts_barrier" ::: "memory")

__device__ __forceinline__ void gload_lds16(const void* g, void* l) {
  __builtin_amdgcn_global_load_lds(
      (const __attribute__((address_space(1))) unsigned int*)g,
      (__attribute__((address_space(3))) unsigned int*)l, 16, 0, 0);
}

__device__ __forceinline__ unsigned pack_h2(float a, float b) {
  return (unsigned)__half_as_ushort(__float2half(a)) |
         ((unsigned)__half_as_ushort(__float2half(b)) << 16);
}

// ---- prep: cast weights to f16 in the layouts the main kernel wants ----
__global__ void __launch_bounds__(512) tt_prep(
    const float* __restrict__ layer0, const float* __restrict__ core1,
    const float* __restrict__ core2, const float* __restrict__ last,
    unsigned char* __restrict__ ws) {
  const int tid = blockIdx.x * 512 + threadIdx.x;
  if (tid < 524288) {                       // ct1/ct2: 2 x 262144 words
    const int which = tid >> 18;
    const int w = tid & 262143;
    const float* core = which ? core2 : core1;
    unsigned char* ct = ws + (which ? WS_CT2 : WS_CT1);
    const int d = w >> 11, rem = w & 2047, s = rem >> 5, j = rem & 31, r = 2 * j;
    const unsigned val = pack_h2(core[r * 8192 + d * 64 + s],
                                 core[(r + 1) * 8192 + d * 64 + s]);
    // byte (2r) within the [s][r] plane XOR-swizzled by ((s&7)<<4)
    *(unsigned*)(ct + d * 8192 + s * 128 + 4 * (j ^ ((s & 7) << 2))) = val;
  } else if (tid < 528384) {                // l0t: 4096 words, [r][d] f16 (256B rows)
    const int w = tid - 524288;
    const int r = w >> 6, j = w & 63, d = 2 * j;
    const unsigned val = pack_h2(layer0[d * 64 + r], layer0[(d + 1) * 64 + r]);
    *(unsigned*)(ws + WS_L0T + r * 256 + 4 * j) = val;
  } else if (tid < 530432) {                // lastT: 2048 words, [o][r] f16 (128B rows)
    const int w = tid - 528384;
    const int o = w >> 5, j = w & 31, r = 2 * j;
    const unsigned val = pack_h2(last[r * 64 + o], last[(r + 1) * 64 + o]);
    *(unsigned*)(ws + WS_LASTT + o * 128 + 4 * j) = val;
  }
}

// ---- fused main kernel: LN + 4-stage tensor-train chain ----
__global__ void __launch_bounds__(512, 4) tt_fused(
    const float* __restrict__ x, const float* __restrict__ lnw,
    const float* __restrict__ lnb, const unsigned char* __restrict__ ws,
    float* __restrict__ out) {
  __shared__ alignas(16) unsigned char smem[SMEM_BYTES];
  const int tid = threadIdx.x;
  const int wid = tid >> 6;
  const int lane = tid & 63;
  const int l31 = lane & 31;
  const int h = lane >> 5;
  const int p  = wid & 1;           // d-parity within chunk
  const int kh = (wid >> 1) & 1;    // r-half (K-split over r)
  const int sb = (wid >> 2) & 1;    // s-block (32 cols)
  const int bg0 = blockIdx.x * TB;
  const int scol = sb * 32 + l31;   // this lane's B-col
  const int sOff = scol * 128;
  const int swzA = (l31 & 7) << 4;  // == (row&7)<<4 for row = mb*32+l31
  const int swzS = swzA;            // == (scol&7)<<4

  float mu8[8], rs8[8];

  // ---------- phase 0: LN stats (kept in regs) + xn0 -> dbuf [row][128d] swz ----------
#pragma unroll
  for (int rr = 0; rr < 8; ++rr) {
    const int row = wid * 8 + rr;
    const float* xrow = x + (size_t)(bg0 + row) * 384;
    float v[6];
#pragma unroll
    for (int k = 0; k < 6; ++k) v[k] = xrow[lane + 64 * k];
    float s = 0.f, ss = 0.f;
#pragma unroll
    for (int k = 0; k < 6; ++k) { s += v[k]; ss += v[k] * v[k]; }
#pragma unroll
    for (int m = 1; m < 64; m <<= 1) { s += __shfl_xor(s, m); ss += __shfl_xor(ss, m); }
    const float mu = s * (1.f / 384.f);
    const float var = ss * (1.f / 384.f) - mu * mu;
    const float rstd = rsqrtf(var + 1e-5f);
    mu8[rr] = mu; rs8[rr] = rstd;
#pragma unroll
    for (int k = 0; k < 6; ++k) {
      const int i = lane + 64 * k;
      if (i % 3 == 0) {
        const int d = i / 3;
        const float xv = (v[k] - mu) * rstd * lnw[d * 3] + lnb[d * 3];
        *(__half*)(smem + DBUF_OFF + row * 256 + ((2 * d) ^ ((row & 7) << 4))) =
            __float2half(xv);
      }
    }
  }
  __syncthreads();

  f32x16 acc[2];  // acc[mb], mb = m-block (rows mb*32..mb*32+31)

  // 4-way (p x kh) cross-wave reduce through LDS scratch, write T (f16 swz)
  auto reduceT = [&]() {
    float* scr = (float*)(smem + DBUF_OFF) + kh * 4096;  // scr0 @0, scr1 @16KB
    __syncthreads();
    if (p == 0) {
#pragma unroll
      for (int mb = 0; mb < 2; ++mb)
#pragma unroll
        for (int j = 0; j < 16; ++j) {
          const int r0 = (j & 3) + 8 * (j >> 2) + 4 * h;
          scr[(mb * 32 + r0) * 64 + scol] = acc[mb][j];
        }
    }
    __syncthreads();
    if (p == 1) {
#pragma unroll
      for (int mb = 0; mb < 2; ++mb)
#pragma unroll
        for (int j = 0; j < 16; ++j) {
          const int r0 = (j & 3) + 8 * (j >> 2) + 4 * h;
          const int idx = (mb * 32 + r0) * 64 + scol;
          scr[idx] += acc[mb][j];
        }
    }
    __syncthreads();
    if (p == 0) {  // wave (kh,sb) combines rows mb==kh across the two r-halves
      const float* s0 = (const float*)(smem + DBUF_OFF);
      const float* s1 = s0 + 4096;
#pragma unroll
      for (int j = 0; j < 16; ++j) {
        const int r0 = (j & 3) + 8 * (j >> 2) + 4 * h;
        const int row = kh * 32 + r0;
        const float vsum = s0[row * 64 + scol] + s1[row * 64 + scol];
        *(__half*)(smem + T_OFF + row * 128 + ((2 * scol) ^ ((row & 7) << 4))) =
            __float2half(vsum);
      }
    }
    __syncthreads();
  };

  // re-normalize x slice sl for d-half hf -> xn [d_local][row], pitch 136B
  auto renorm = [&](int sl, int hf) {
#pragma unroll
    for (int rr = 0; rr < 8; ++rr) {
      const int row = wid * 8 + rr;
      const float* xrow = x + (size_t)(bg0 + row) * 384 + hf * 192;
      const float mu = mu8[rr], rstd = rs8[rr];
#pragma unroll
      for (int k = 0; k < 3; ++k) {
        const int i = lane + 64 * k;        // hf*192 is divisible by 3
        if (i % 3 == sl) {
          const int dg = (hf * 192 + i) / 3;
          const int dl = dg - hf * 64;
          const float xv = (xrow[i] - mu) * rstd * lnw[dg * 3 + sl] + lnb[dg * 3 + sl];
          *(__half*)(smem + XN_OFF + dl * 136 + 2 * row) = __float2half(xv);
        }
      }
    }
  };

  // issue one 32KB core chunk (4 d's) into dbuf buffer `buf`
  auto issue_chunk = [&](const unsigned char* ctg, int cg, int buf) {
    const unsigned char* g = ctg + cg * 32768 + tid * 16;
    unsigned char* l = smem + DBUF_OFF + buf * 32768 + tid * 16;
    gload_lds16(g, l);
    gload_lds16(g + 8192, l + 8192);
    gload_lds16(g + 16384, l + 16384);
    gload_lds16(g + 24576, l + 24576);
  };

  // ---------- stage A: T1 = xn0 @ layer0 (K=128, 4-way (p,kh) K-split) ----------
#pragma unroll
  for (int i = 0; i < 16; ++i) { acc[0][i] = 0.f; acc[1][i] = 0.f; }
  {
    const unsigned char* l0t = ws + WS_L0T;
#pragma unroll
    for (int kbL = 0; kbL < 2; ++kbL) {
      const int cb = (((p << 1) | kh) * 2 + kbL) * 32 + h * 16;
      f16x8 bf = *(const f16x8*)(l0t + scol * 256 + cb);
      f16x8 a0 = *(const f16x8*)(smem + DBUF_OFF + l31 * 256 + (cb ^ swzA));
      f16x8 a1 = *(const f16x8*)(smem + DBUF_OFF + (32 + l31) * 256 + (cb ^ swzA));
      acc[0] = __builtin_amdgcn_mfma_f32_32x32x16_f16(a0, bf, acc[0], 0, 0, 0);
      acc[1] = __builtin_amdgcn_mfma_f32_32x32x16_f16(a1, bf, acc[1], 0, 0, 0);
    }
  }
  reduceT();  // -> T1

  // ---------- stages B,C: T = KR(T, xn_l) @ core_l ----------
  for (int st = 0; st < 2; ++st) {
    const int sl = st + 1;
    const unsigned char* ctg = ws + (st ? WS_CT2 : WS_CT1);

    issue_chunk(ctg, 0, 0);  // prologue: chunk 0 (dbuf free after reduceT)

    // T rows (both m-blocks x this wave's r-half K=32) into packed regs
    H2x4 t1pk[2][2];
#pragma unroll
    for (int mb = 0; mb < 2; ++mb)
#pragma unroll
      for (int kbL = 0; kbL < 2; ++kbL)
        t1pk[mb][kbL].v = *(const f16x8*)(smem + T_OFF + (mb * 32 + l31) * 128 +
                                          (((kh * 2 + kbL) * 32 + h * 16) ^ swzA));
    __syncthreads();  // t1pk read done before renorm overwrites the T/xn alias

#pragma unroll
    for (int i = 0; i < 16; ++i) { acc[0][i] = 0.f; acc[1][i] = 0.f; }

    int cur = 0;  // double-buffer index (wave-uniform)
    for (int hf = 0; hf < 2; ++hf) {
      renorm(sl, hf);
      __syncthreads();  // xn visible; also drains in-flight chunk loads
#pragma unroll 1
      for (int c4 = 0; c4 < 16; ++c4) {
        const int cg = hf * 16 + c4;
        if (c4 != 0) WAITBAR0();            // chunk cg's loads done, all waves synced
        if (cg != 31) issue_chunk(ctg, cg + 1, cur ^ 1);  // overlaps compute(cg)
        // compute chunk cg: this wave's d's have parity p (dloc = p, p+2)
        const unsigned char* bufp = smem + DBUF_OFF + cur * 32768;
#pragma unroll
        for (int dh = 0; dh < 2; ++dh) {
          const int dloc = p + 2 * dh;
          const int xoff = XN_OFF + (4 * c4 + dloc) * 136 + 2 * l31;
          const unsigned xv0 = *(const unsigned short*)(smem + xoff);
          const unsigned xv1 = *(const unsigned short*)(smem + xoff + 64);
          U1H2 d0, d1;
          d0.u = xv0 | (xv0 << 16);
          d1.u = xv1 | (xv1 << 16);
          const unsigned char* bp = bufp + dloc * 8192 + sOff;
#pragma unroll
          for (int kbL = 0; kbL < 2; ++kbL) {
            f16x8 bf = *(const f16x8*)(bp + (((kh * 2 + kbL) * 32 + h * 16) ^ swzS));
            H2x4 af0, af1;
#pragma unroll
            for (int i = 0; i < 4; ++i) {
              af0.h2[i] = __hmul2(t1pk[0][kbL].h2[i], d0.h);
              af1.h2[i] = __hmul2(t1pk[1][kbL].h2[i], d1.h);
            }
            acc[0] = __builtin_amdgcn_mfma_f32_32x32x16_f16(af0.v, bf, acc[0], 0, 0, 0);
            acc[1] = __builtin_amdgcn_mfma_f32_32x32x16_f16(af1.v, bf, acc[1], 0, 0, 0);
          }
        }
        cur ^= 1;
      }
    }
    reduceT();  // -> T2 then T3
  }

  // ---------- stage D: out = T3 @ last (p==0 waves; mb = kh) ----------
  if (p == 0) {
    f32x16 accd;
#pragma unroll
    for (int i = 0; i < 16; ++i) accd[i] = 0.f;
    const unsigned char* lastT = ws + WS_LASTT;
#pragma unroll
    for (int kb = 0; kb < 4; ++kb) {
      const int cb = kb * 32 + h * 16;
      f16x8 bf = *(const f16x8*)(lastT + scol * 128 + cb);
      f16x8 af = *(const f16x8*)(smem + T_OFF + (kh * 32 + l31) * 128 + (cb ^ swzA));
      accd = __builtin_amdgcn_mfma_f32_32x32x16_f16(af, bf, accd, 0, 0, 0);
    }
#pragma unroll
    for (int j = 0; j < 16; ++j) {
      const int r0 = (j & 3) + 8 * (j >> 2) + 4 * h;
      out[(size_t)(bg0 + kh * 32 + r0) * 64 + scol] = accd[j];
    }
  }
}

extern "C" void kernel_launch(void* const* d_in, const int* in_sizes, int n_in,
                              void* d_out, int out_size, void* d_ws, size_t ws_size,
                              hipStream_t stream) {
  const float* x      = (const float*)d_in[0];
  const float* layer0 = (const float*)d_in[1];
  const float* core1  = (const float*)d_in[2];
  const float* core2  = (const float*)d_in[3];
  const float* last   = (const float*)d_in[4];
  const float* lnw    = (const float*)d_in[5];
  const float* lnb    = (const float*)d_in[6];
  unsigned char* ws   = (unsigned char*)d_ws;
  float* outp         = (float*)d_out;

  tt_prep<<<1036, 512, 0, stream>>>(layer0, core1, core2, last, ws);
  tt_fused<<<512, 512, 0, stream>>>(x, lnw, lnb, ws, outp);
}

// Round 2
// 155.322 us; speedup vs baseline: 1.1515x; 1.1515x over previous
//
#include <hip/hip_runtime.h>
#include <hip/hip_fp16.h>

// B=32768, D=128, L=3, R=64, O=64. fp32 in/out, f16 MFMA compute.
// Wave split: p = d-parity, kh = r-half (K-split), sb = s-half; M-unroll 2
// -> core chunk LDS reads are read-once. 16 KB chunks in a 4-slot ring with
// 2-ahead prefetch (counted vmcnt(4)). All accumulator state in NAMED
// registers (no arrays captured by reference); LN stats live in LDS.
typedef _Float16 f16x8 __attribute__((ext_vector_type(8)));
typedef float f32x16 __attribute__((ext_vector_type(16)));

union H2x4 { f16x8 v; __half2 h2[4]; unsigned u[4]; };
union U1H2 { unsigned u; __half2 h; };

#define TB 64               // batch rows per workgroup (512 WGs = 2/CU)
// LDS layout (bytes)
#define DBUF_OFF 0          // 4 x 16KB core chunk ring (+ reduce scratch in 0/1)
#define T_OFF    65536      // T buffer [64][64]f16, 128B rows, XOR swz = 8192B
#define XN_OFF   65536      // xn half-slice ALIASES T: [dl<64][row<64] pitch 136B
#define STATS_OFF 74240     // 64 x {mu, rstd} f32 = 512B
#define SMEM_BYTES 74752    // 2 WGs/CU (149504 <= 160K)
// workspace layout (bytes)
#define WS_CT1   0          // core1 -> [d][s][r] f16, swizzled, 1MB
#define WS_CT2   1048576    // core2 same
#define WS_L0T   2097152    // layer0^T [r][d] f16, 16KB
#define WS_LASTT 2113536    // last^T [o][r] f16, 8KB

#define WAITBAR4() asm volatile("s_waitcnt vmcnt(4)\n\ts_barrier" ::: "memory")
#define WAITBAR2() asm volatile("s_waitcnt vmcnt(2)\n\ts_barrier" ::: "memory")
#define WAITBAR0() asm volatile("s_waitcnt vmcnt(0)\n\ts_barrier" ::: "memory")

__device__ __forceinline__ void gload_lds16(const void* g, void* l) {
  __builtin_amdgcn_global_load_lds(
      (const __attribute__((address_space(1))) unsigned int*)g,
      (__attribute__((address_space(3))) unsigned int*)l, 16, 0, 0);
}

// stage one 16KB core chunk (2 d's): 2 loads/thread
__device__ __forceinline__ void issue_chunk16(const unsigned char* g,
                                              unsigned char* l, int tid) {
  gload_lds16(g + tid * 16, l + tid * 16);
  gload_lds16(g + tid * 16 + 8192, l + tid * 16 + 8192);
}

__device__ __forceinline__ unsigned pack_h2(float a, float b) {
  return (unsigned)__half_as_ushort(__float2half(a)) |
         ((unsigned)__half_as_ushort(__float2half(b)) << 16);
}

// 4-way (p x kh) cross-wave reduce through LDS scratch (ring slots 0/1),
// writes T [64][64] f16 swizzled. Accumulators passed BY VALUE (regs).
__device__ __forceinline__ void reduce_T(unsigned char* smem, f32x16 a0, f32x16 a1,
                                         int p, int kh, int h, int scol) {
  float* scr = (float*)(smem + DBUF_OFF) + kh * 4096;  // scr0 @0, scr1 @16KB
  __syncthreads();
  if (p == 0) {
#pragma unroll
    for (int j = 0; j < 16; ++j) {
      const int r0 = (j & 3) + 8 * (j >> 2) + 4 * h;
      scr[r0 * 64 + scol] = a0[j];
      scr[(32 + r0) * 64 + scol] = a1[j];
    }
  }
  __syncthreads();
  if (p == 1) {
#pragma unroll
    for (int j = 0; j < 16; ++j) {
      const int r0 = (j & 3) + 8 * (j >> 2) + 4 * h;
      scr[r0 * 64 + scol] += a0[j];
      scr[(32 + r0) * 64 + scol] += a1[j];
    }
  }
  __syncthreads();
  if (p == 0) {  // wave (kh,sb) combines rows kh*32.. across the two r-halves
    const float* s0 = (const float*)(smem + DBUF_OFF);
    const float* s1 = s0 + 4096;
#pragma unroll
    for (int j = 0; j < 16; ++j) {
      const int r0 = (j & 3) + 8 * (j >> 2) + 4 * h;
      const int row = kh * 32 + r0;
      const float vsum = s0[row * 64 + scol] + s1[row * 64 + scol];
      *(__half*)(smem + T_OFF + row * 128 + ((2 * scol) ^ ((row & 7) << 4))) =
          __float2half(vsum);
    }
  }
  __syncthreads();
}

// re-normalize x slice sl for d-half hf -> xn [d_local][row], pitch 136B.
// LN stats read from LDS (wave-uniform broadcast).
__device__ __forceinline__ void renorm_slice(unsigned char* smem, const float* x,
                                             const float* lnw, const float* lnb,
                                             int bg0, int wid, int lane, int sl,
                                             int hf) {
  const float* stats = (const float*)(smem + STATS_OFF);
#pragma unroll
  for (int rr = 0; rr < 8; ++rr) {
    const int row = wid * 8 + rr;
    const float* xrow = x + (size_t)(bg0 + row) * 384 + hf * 192;
    const float mu = stats[2 * row], rstd = stats[2 * row + 1];
#pragma unroll
    for (int k = 0; k < 3; ++k) {
      const int i = lane + 64 * k;          // hf*192 is divisible by 3
      if (i % 3 == sl) {
        const int dg = (hf * 192 + i) / 3;
        const int dl = dg - hf * 64;
        const float xv = (xrow[i] - mu) * rstd * lnw[dg * 3 + sl] + lnb[dg * 3 + sl];
        *(__half*)(smem + XN_OFF + dl * 136 + 2 * row) = __float2half(xv);
      }
    }
  }
}

// ---- prep: cast weights to f16 in the layouts the main kernel wants ----
__global__ void __launch_bounds__(512) tt_prep(
    const float* __restrict__ layer0, const float* __restrict__ core1,
    const float* __restrict__ core2, const float* __restrict__ last,
    unsigned char* __restrict__ ws) {
  const int tid = blockIdx.x * 512 + threadIdx.x;
  if (tid < 524288) {                       // ct1/ct2: 2 x 262144 words
    const int which = tid >> 18;
    const int w = tid & 262143;
    const float* core = which ? core2 : core1;
    unsigned char* ct = ws + (which ? WS_CT2 : WS_CT1);
    const int d = w >> 11, rem = w & 2047, s = rem >> 5, j = rem & 31, r = 2 * j;
    const unsigned val = pack_h2(core[r * 8192 + d * 64 + s],
                                 core[(r + 1) * 8192 + d * 64 + s]);
    // byte (2r) within the [s][r] plane XOR-swizzled by ((s&7)<<4)
    *(unsigned*)(ct + d * 8192 + s * 128 + 4 * (j ^ ((s & 7) << 2))) = val;
  } else if (tid < 528384) {                // l0t: 4096 words, [r][d] f16 (256B rows)
    const int w = tid - 524288;
    const int r = w >> 6, j = w & 63, d = 2 * j;
    const unsigned val = pack_h2(layer0[d * 64 + r], layer0[(d + 1) * 64 + r]);
    *(unsigned*)(ws + WS_L0T + r * 256 + 4 * j) = val;
  } else if (tid < 530432) {                // lastT: 2048 words, [o][r] f16 (128B rows)
    const int w = tid - 528384;
    const int o = w >> 5, j = w & 31, r = 2 * j;
    const unsigned val = pack_h2(last[r * 64 + o], last[(r + 1) * 64 + o]);
    *(unsigned*)(ws + WS_LASTT + o * 128 + 4 * j) = val;
  }
}

// ---- fused main kernel: LN + 4-stage tensor-train chain ----
__global__ void __launch_bounds__(512, 4) tt_fused(
    const float* __restrict__ x, const float* __restrict__ lnw,
    const float* __restrict__ lnb, const unsigned char* __restrict__ ws,
    float* __restrict__ out) {
  __shared__ alignas(16) unsigned char smem[SMEM_BYTES];
  const int tid = threadIdx.x;
  const int wid = tid >> 6;
  const int lane = tid & 63;
  const int l31 = lane & 31;
  const int h = lane >> 5;
  const int p  = wid & 1;           // d-parity within chunk
  const int kh = (wid >> 1) & 1;    // r-half (K-split over r)
  const int sb = (wid >> 2) & 1;    // s-block (32 cols)
  const int bg0 = blockIdx.x * TB;
  const int scol = sb * 32 + l31;   // this lane's B-col
  const int sOff = scol * 128;
  const int swzA = (l31 & 7) << 4;  // == (row&7)<<4 for row = mb*32+l31
  const int swzS = swzA;            // == (scol&7)<<4

  // ---------- phase 0: LN stats -> LDS + xn0 -> ring slot0/1 [row][128d] swz ----------
  {
    float* stats = (float*)(smem + STATS_OFF);
#pragma unroll
    for (int rr = 0; rr < 8; ++rr) {
      const int row = wid * 8 + rr;
      const float* xrow = x + (size_t)(bg0 + row) * 384;
      float v[6];
#pragma unroll
      for (int k = 0; k < 6; ++k) v[k] = xrow[lane + 64 * k];
      float s = 0.f, ss = 0.f;
#pragma unroll
      for (int k = 0; k < 6; ++k) { s += v[k]; ss += v[k] * v[k]; }
#pragma unroll
      for (int m = 1; m < 64; m <<= 1) { s += __shfl_xor(s, m); ss += __shfl_xor(ss, m); }
      const float mu = s * (1.f / 384.f);
      const float var = ss * (1.f / 384.f) - mu * mu;
      const float rstd = rsqrtf(var + 1e-5f);
      if (lane == 0) { stats[2 * row] = mu; stats[2 * row + 1] = rstd; }
#pragma unroll
      for (int k = 0; k < 6; ++k) {
        const int i = lane + 64 * k;
        if (i % 3 == 0) {
          const int d = i / 3;
          const float xv = (v[k] - mu) * rstd * lnw[d * 3] + lnb[d * 3];
          *(__half*)(smem + DBUF_OFF + row * 256 + ((2 * d) ^ ((row & 7) << 4))) =
              __float2half(xv);
        }
      }
    }
  }
  __syncthreads();

  f32x16 acc0, acc1;  // rows 0..31 / 32..63 of this wave's (kh,sb) partial

  // ---------- stage A: T1 = xn0 @ layer0 (K=128, 4-way (p,kh) K-split) ----------
#pragma unroll
  for (int i = 0; i < 16; ++i) { acc0[i] = 0.f; acc1[i] = 0.f; }
  {
    const unsigned char* l0t = ws + WS_L0T;
#pragma unroll
    for (int kbL = 0; kbL < 2; ++kbL) {
      const int cb = (((p << 1) | kh) * 2 + kbL) * 32 + h * 16;
      f16x8 bf = *(const f16x8*)(l0t + scol * 256 + cb);
      f16x8 a0 = *(const f16x8*)(smem + DBUF_OFF + l31 * 256 + (cb ^ swzA));
      f16x8 a1 = *(const f16x8*)(smem + DBUF_OFF + (32 + l31) * 256 + (cb ^ swzA));
      acc0 = __builtin_amdgcn_mfma_f32_32x32x16_f16(a0, bf, acc0, 0, 0, 0);
      acc1 = __builtin_amdgcn_mfma_f32_32x32x16_f16(a1, bf, acc1, 0, 0, 0);
    }
  }
  reduce_T(smem, acc0, acc1, p, kh, h, scol);  // -> T1

  // ---------- stages B,C: T = KR(T, xn_l) @ core_l ----------
  for (int st = 0; st < 2; ++st) {
    const int sl = st + 1;
    const unsigned char* ctg = ws + (st ? WS_CT2 : WS_CT1);

    // prologue: chunks 0,1 -> ring slots 0,1 (ring free after reduce_T's sync)
    issue_chunk16(ctg, smem + DBUF_OFF, tid);
    issue_chunk16(ctg + 16384, smem + DBUF_OFF + 16384, tid);

    // T rows (both m-blocks x this wave's r-half K=32) into NAMED packed regs
    H2x4 tp00, tp01, tp10, tp11;   // tp<mb><kbL>
    {
      const int rb0 = kh * 64 + h * 16;
      tp00.v = *(const f16x8*)(smem + T_OFF + l31 * 128 + (rb0 ^ swzA));
      tp01.v = *(const f16x8*)(smem + T_OFF + l31 * 128 + ((rb0 + 32) ^ swzA));
      tp10.v = *(const f16x8*)(smem + T_OFF + (32 + l31) * 128 + (rb0 ^ swzA));
      tp11.v = *(const f16x8*)(smem + T_OFF + (32 + l31) * 128 + ((rb0 + 32) ^ swzA));
    }
    __syncthreads();  // T consumed before renorm overwrites the T/xn alias

#pragma unroll
    for (int i = 0; i < 16; ++i) { acc0[i] = 0.f; acc1[i] = 0.f; }

    for (int hf = 0; hf < 2; ++hf) {
      renorm_slice(smem, x, lnw, lnb, bg0, wid, lane, sl, hf);
      __syncthreads();  // xn visible (chunk loads stay in flight across this)
#pragma unroll 1
      for (int c = 0; c < 32; ++c) {
        const int cg = hf * 32 + c;
        // 2-ahead prefetch into ring slot (cg+2)&3: that slot was last read
        // at iteration cg-2 -> one full barrier separation -> race-free.
        if (cg <= 61) {
          issue_chunk16(ctg + (cg + 2) * 16384,
                        smem + DBUF_OFF + ((cg + 2) & 3) * 16384, tid);
          WAITBAR4();   // drain chunk cg; leave cg+1, cg+2 in flight
        } else if (cg == 62) {
          WAITBAR2();
        } else {
          WAITBAR0();
        }
        // compute chunk cg: this wave's d has parity p (1 d per 16KB chunk)
        const unsigned char* bp =
            smem + DBUF_OFF + (cg & 3) * 16384 + p * 8192 + sOff;
        const int xoff = XN_OFF + (2 * c + p) * 136 + 2 * l31;
        const unsigned xv0 = *(const unsigned short*)(smem + xoff);
        const unsigned xv1 = *(const unsigned short*)(smem + xoff + 64);
        U1H2 d0, d1;
        d0.u = xv0 | (xv0 << 16);
        d1.u = xv1 | (xv1 << 16);
        const int rb = kh * 64 + h * 16;
        {  // kbL = 0
          f16x8 bf = *(const f16x8*)(bp + (rb ^ swzS));
          H2x4 af0, af1;
#pragma unroll
          for (int i = 0; i < 4; ++i) {
            af0.h2[i] = __hmul2(tp00.h2[i], d0.h);
            af1.h2[i] = __hmul2(tp10.h2[i], d1.h);
          }
          acc0 = __builtin_amdgcn_mfma_f32_32x32x16_f16(af0.v, bf, acc0, 0, 0, 0);
          acc1 = __builtin_amdgcn_mfma_f32_32x32x16_f16(af1.v, bf, acc1, 0, 0, 0);
        }
        {  // kbL = 1
          f16x8 bf = *(const f16x8*)(bp + ((rb + 32) ^ swzS));
          H2x4 af0, af1;
#pragma unroll
          for (int i = 0; i < 4; ++i) {
            af0.h2[i] = __hmul2(tp01.h2[i], d0.h);
            af1.h2[i] = __hmul2(tp11.h2[i], d1.h);
          }
          acc0 = __builtin_amdgcn_mfma_f32_32x32x16_f16(af0.v, bf, acc0, 0, 0, 0);
          acc1 = __builtin_amdgcn_mfma_f32_32x32x16_f16(af1.v, bf, acc1, 0, 0, 0);
        }
      }
    }
    reduce_T(smem, acc0, acc1, p, kh, h, scol);  // -> T2 then T3
  }

  // ---------- stage D: out = T3 @ last (p==0 waves; rows kh*32..) ----------
  if (p == 0) {
    f32x16 accd;
#pragma unroll
    for (int i = 0; i < 16; ++i) accd[i] = 0.f;
    const unsigned char* lastT = ws + WS_LASTT;
#pragma unroll
    for (int kb = 0; kb < 4; ++kb) {
      const int cb = kb * 32 + h * 16;
      f16x8 bf = *(const f16x8*)(lastT + scol * 128 + cb);
      f16x8 af = *(const f16x8*)(smem + T_OFF + (kh * 32 + l31) * 128 + (cb ^ swzA));
      accd = __builtin_amdgcn_mfma_f32_32x32x16_f16(af, bf, accd, 0, 0, 0);
    }
#pragma unroll
    for (int j = 0; j < 16; ++j) {
      const int r0 = (j & 3) + 8 * (j >> 2) + 4 * h;
      out[(size_t)(bg0 + kh * 32 + r0) * 64 + scol] = accd[j];
    }
  }
}

extern "C" void kernel_launch(void* const* d_in, const int* in_sizes, int n_in,
                              void* d_out, int out_size, void* d_ws, size_t ws_size,
                              hipStream_t stream) {
  const float* x      = (const float*)d_in[0];
  const float* layer0 = (const float*)d_in[1];
  const float* core1  = (const float*)d_in[2];
  const float* core2  = (const float*)d_in[3];
  const float* last   = (const float*)d_in[4];
  const float* lnw    = (const float*)d_in[5];
  const float* lnb    = (const float*)d_in[6];
  unsigned char* ws   = (unsigned char*)d_ws;
  float* outp         = (float*)d_out;

  tt_prep<<<1036, 512, 0, stream>>>(layer0, core1, core2, last, ws);
  tt_fused<<<512, 512, 0, stream>>>(x, lnw, lnb, ws, outp);
}

// Round 3
// 108.099 us; speedup vs baseline: 1.6546x; 1.4369x over previous
//
#include <hip/hip_runtime.h>
#include <hip/hip_fp16.h>

// B=32768, D=128, L=3, R=64, O=64. fp32 in/out, f16 MFMA compute.
// Wave split: p = d-parity, kh = r-half (K-split), sb = s-half; M-unroll 2
// -> core chunk LDS reads are read-once. x is read EXACTLY ONCE: phase 0
// computes all three xn slices; slices 1,2 stay resident in LDS (xn12).
// 2-slot ring, issue-after-barrier 1-ahead prefetch. All accumulator state
// in NAMED registers.
typedef _Float16 f16x8 __attribute__((ext_vector_type(8)));
typedef float f32x16 __attribute__((ext_vector_type(16)));

union H2x4 { f16x8 v; __half2 h2[4]; unsigned u[4]; };
union U1H2 { unsigned u; __half2 h; };

#define TB 64               // batch rows per workgroup (512 WGs = 2/CU)
// LDS layout (bytes)
#define RING_OFF 0          // 2 x 16KB core chunk ring (+ reduce scratch + xn0)
#define T_OFF    32768      // T buffer [64][64]f16, 128B rows, XOR swz = 8192B
#define XN12_OFF 40960      // xn slices 1,2: [d<128][row<64] 2xf16, pitch 264B = 33792B
#define SMEM_BYTES 74752    // 2 WGs/CU (149504 <= 163840)
// workspace layout (bytes)
#define WS_CT1   0          // core1 -> [d][s][r] f16, swizzled, 1MB
#define WS_CT2   1048576    // core2 same
#define WS_L0T   2097152    // layer0^T [r][d] f16, 16KB
#define WS_LASTT 2113536    // last^T [o][r] f16, 8KB

#define WAITBAR0() asm volatile("s_waitcnt vmcnt(0)\n\ts_barrier" ::: "memory")

__device__ __forceinline__ void gload_lds16(const void* g, void* l) {
  __builtin_amdgcn_global_load_lds(
      (const __attribute__((address_space(1))) unsigned int*)g,
      (__attribute__((address_space(3))) unsigned int*)l, 16, 0, 0);
}

// stage one 16KB core chunk (2 d's): 2 loads/thread
__device__ __forceinline__ void issue_chunk16(const unsigned char* g,
                                              unsigned char* l, int tid) {
  gload_lds16(g + tid * 16, l + tid * 16);
  gload_lds16(g + tid * 16 + 8192, l + tid * 16 + 8192);
}

__device__ __forceinline__ unsigned pack_h2(float a, float b) {
  return (unsigned)__half_as_ushort(__float2half(a)) |
         ((unsigned)__half_as_ushort(__float2half(b)) << 16);
}

// 4-way (p x kh) cross-wave reduce through LDS scratch (ring slots 0/1),
// writes T [64][64] f16 swizzled. Accumulators passed BY VALUE (regs).
__device__ __forceinline__ void reduce_T(unsigned char* smem, f32x16 a0, f32x16 a1,
                                         int p, int kh, int h, int scol) {
  float* scr = (float*)(smem + RING_OFF) + kh * 4096;  // scr0 @0, scr1 @16KB
  __syncthreads();
  if (p == 0) {
#pragma unroll
    for (int j = 0; j < 16; ++j) {
      const int r0 = (j & 3) + 8 * (j >> 2) + 4 * h;
      scr[r0 * 64 + scol] = a0[j];
      scr[(32 + r0) * 64 + scol] = a1[j];
    }
  }
  __syncthreads();
  if (p == 1) {
#pragma unroll
    for (int j = 0; j < 16; ++j) {
      const int r0 = (j & 3) + 8 * (j >> 2) + 4 * h;
      scr[r0 * 64 + scol] += a0[j];
      scr[(32 + r0) * 64 + scol] += a1[j];
    }
  }
  __syncthreads();
  if (p == 0) {  // wave (kh,sb) combines rows kh*32.. across the two r-halves
    const float* s0 = (const float*)(smem + RING_OFF);
    const float* s1 = s0 + 4096;
#pragma unroll
    for (int j = 0; j < 16; ++j) {
      const int r0 = (j & 3) + 8 * (j >> 2) + 4 * h;
      const int row = kh * 32 + r0;
      const float vsum = s0[row * 64 + scol] + s1[row * 64 + scol];
      *(__half*)(smem + T_OFF + row * 128 + ((2 * scol) ^ ((row & 7) << 4))) =
          __float2half(vsum);
    }
  }
  __syncthreads();
}

// ---- prep: cast weights to f16 in the layouts the main kernel wants ----
__global__ void __launch_bounds__(512) tt_prep(
    const float* __restrict__ layer0, const float* __restrict__ core1,
    const float* __restrict__ core2, const float* __restrict__ last,
    unsigned char* __restrict__ ws) {
  const int tid = blockIdx.x * 512 + threadIdx.x;
  if (tid < 524288) {                       // ct1/ct2: 2 x 262144 words
    const int which = tid >> 18;
    const int w = tid & 262143;
    const float* core = which ? core2 : core1;
    unsigned char* ct = ws + (which ? WS_CT2 : WS_CT1);
    const int d = w >> 11, rem = w & 2047, s = rem >> 5, j = rem & 31, r = 2 * j;
    const unsigned val = pack_h2(core[r * 8192 + d * 64 + s],
                                 core[(r + 1) * 8192 + d * 64 + s]);
    // byte (2r) within the [s][r] plane XOR-swizzled by ((s&7)<<4)
    *(unsigned*)(ct + d * 8192 + s * 128 + 4 * (j ^ ((s & 7) << 2))) = val;
  } else if (tid < 528384) {                // l0t: 4096 words, [r][d] f16 (256B rows)
    const int w = tid - 524288;
    const int r = w >> 6, j = w & 63, d = 2 * j;
    const unsigned val = pack_h2(layer0[d * 64 + r], layer0[(d + 1) * 64 + r]);
    *(unsigned*)(ws + WS_L0T + r * 256 + 4 * j) = val;
  } else if (tid < 530432) {                // lastT: 2048 words, [o][r] f16 (128B rows)
    const int w = tid - 528384;
    const int o = w >> 5, j = w & 31, r = 2 * j;
    const unsigned val = pack_h2(last[r * 64 + o], last[(r + 1) * 64 + o]);
    *(unsigned*)(ws + WS_LASTT + o * 128 + 4 * j) = val;
  }
}

// ---- fused main kernel: LN + 4-stage tensor-train chain ----
__global__ void __launch_bounds__(512, 4) tt_fused(
    const float* __restrict__ x, const float* __restrict__ lnw,
    const float* __restrict__ lnb, const unsigned char* __restrict__ ws,
    float* __restrict__ out) {
  __shared__ alignas(16) unsigned char smem[SMEM_BYTES];
  const int tid = threadIdx.x;
  const int wid = tid >> 6;
  const int lane = tid & 63;
  const int l31 = lane & 31;
  const int h = lane >> 5;
  const int p  = wid & 1;           // d-parity within chunk
  const int kh = (wid >> 1) & 1;    // r-half (K-split over r)
  const int sb = (wid >> 2) & 1;    // s-block (32 cols)
  const int bg0 = blockIdx.x * TB;
  const int scol = sb * 32 + l31;   // this lane's B-col
  const int sOff = scol * 128;
  const int swzA = (l31 & 7) << 4;  // == (row&7)<<4 for row = mb*32+l31
  const int swzS = swzA;            // == (scol&7)<<4

  // ---------- phase 0: LN; xn0 -> ring slot0 [row][256B swz]; xn1,2 -> xn12 ----------
  {
    float wv[6], bv[6];
#pragma unroll
    for (int k = 0; k < 6; ++k) { wv[k] = lnw[lane + 64 * k]; bv[k] = lnb[lane + 64 * k]; }
#pragma unroll
    for (int rr = 0; rr < 8; ++rr) {
      const int row = wid * 8 + rr;
      const float* xrow = x + (size_t)(bg0 + row) * 384;
      float v[6];
#pragma unroll
      for (int k = 0; k < 6; ++k) v[k] = xrow[lane + 64 * k];
      float s = 0.f, ss = 0.f;
#pragma unroll
      for (int k = 0; k < 6; ++k) { s += v[k]; ss += v[k] * v[k]; }
#pragma unroll
      for (int m = 1; m < 64; m <<= 1) { s += __shfl_xor(s, m); ss += __shfl_xor(ss, m); }
      const float mu = s * (1.f / 384.f);
      const float var = ss * (1.f / 384.f) - mu * mu;
      const float rstd = rsqrtf(var + 1e-5f);
#pragma unroll
      for (int k = 0; k < 6; ++k) {
        const int i = lane + 64 * k;        // i = 3*d + sl
        const int d = i / 3;
        const int sl = i - 3 * d;
        const float xv = (v[k] - mu) * rstd * wv[k] + bv[k];
        if (sl == 0) {
          *(__half*)(smem + RING_OFF + row * 256 + ((2 * d) ^ ((row & 7) << 4))) =
              __float2half(xv);
        } else {
          *(__half*)(smem + XN12_OFF + d * 264 + 4 * row + 2 * (sl - 1)) =
              __float2half(xv);
        }
      }
    }
  }
  __syncthreads();

  f32x16 acc0, acc1;  // rows 0..31 / 32..63 of this wave's (kh,sb) partial

  // ---------- stage A: T1 = xn0 @ layer0 (K=128, 4-way (p,kh) K-split) ----------
#pragma unroll
  for (int i = 0; i < 16; ++i) { acc0[i] = 0.f; acc1[i] = 0.f; }
  {
    const unsigned char* l0t = ws + WS_L0T;
#pragma unroll
    for (int kbL = 0; kbL < 2; ++kbL) {
      const int cb = (((p << 1) | kh) * 2 + kbL) * 32 + h * 16;
      f16x8 bf = *(const f16x8*)(l0t + scol * 256 + cb);
      f16x8 a0 = *(const f16x8*)(smem + RING_OFF + l31 * 256 + (cb ^ swzA));
      f16x8 a1 = *(const f16x8*)(smem + RING_OFF + (32 + l31) * 256 + (cb ^ swzA));
      acc0 = __builtin_amdgcn_mfma_f32_32x32x16_f16(a0, bf, acc0, 0, 0, 0);
      acc1 = __builtin_amdgcn_mfma_f32_32x32x16_f16(a1, bf, acc1, 0, 0, 0);
    }
  }
  reduce_T(smem, acc0, acc1, p, kh, h, scol);  // -> T1

  // ---------- stages B,C: T = KR(T, xn_l) @ core_l ----------
  for (int st = 0; st < 2; ++st) {
    const unsigned char* ctg = ws + (st ? WS_CT2 : WS_CT1);

    // prologue: chunk 0 -> ring slot 0 (ring free after reduce_T's final sync)
    issue_chunk16(ctg, smem + RING_OFF, tid);

    // T rows (both m-blocks x this wave's r-half K=32) into NAMED packed regs
    H2x4 tp00, tp01, tp10, tp11;   // tp<mb><kbL>
    {
      const int rb0 = kh * 64 + h * 16;
      tp00.v = *(const f16x8*)(smem + T_OFF + l31 * 128 + (rb0 ^ swzA));
      tp01.v = *(const f16x8*)(smem + T_OFF + l31 * 128 + ((rb0 + 32) ^ swzA));
      tp10.v = *(const f16x8*)(smem + T_OFF + (32 + l31) * 128 + (rb0 ^ swzA));
      tp11.v = *(const f16x8*)(smem + T_OFF + (32 + l31) * 128 + ((rb0 + 32) ^ swzA));
    }

#pragma unroll
    for (int i = 0; i < 16; ++i) { acc0[i] = 0.f; acc1[i] = 0.f; }

#pragma unroll 1
    for (int cg = 0; cg < 64; ++cg) {
      // drain chunk cg's loads (issued one full iteration ago), sync, then
      // issue cg+1 into the slot whose readers all passed this barrier.
      WAITBAR0();
      if (cg < 63)
        issue_chunk16(ctg + (cg + 1) * 16384,
                      smem + RING_OFF + ((cg + 1) & 1) * 16384, tid);
      // compute chunk cg: this wave's d = 2*cg + p
      const unsigned char* bp =
          smem + RING_OFF + (cg & 1) * 16384 + p * 8192 + sOff;
      const unsigned char* xp =
          smem + XN12_OFF + (2 * cg + p) * 264 + 2 * st + 4 * l31;
      const unsigned xv0 = *(const unsigned short*)(xp);
      const unsigned xv1 = *(const unsigned short*)(xp + 128);
      U1H2 d0, d1;
      d0.u = xv0 | (xv0 << 16);
      d1.u = xv1 | (xv1 << 16);
      const int rb = kh * 64 + h * 16;
      {  // kbL = 0
        f16x8 bf = *(const f16x8*)(bp + (rb ^ swzS));
        H2x4 af0, af1;
#pragma unroll
        for (int i = 0; i < 4; ++i) {
          af0.h2[i] = __hmul2(tp00.h2[i], d0.h);
          af1.h2[i] = __hmul2(tp10.h2[i], d1.h);
        }
        acc0 = __builtin_amdgcn_mfma_f32_32x32x16_f16(af0.v, bf, acc0, 0, 0, 0);
        acc1 = __builtin_amdgcn_mfma_f32_32x32x16_f16(af1.v, bf, acc1, 0, 0, 0);
      }
      {  // kbL = 1
        f16x8 bf = *(const f16x8*)(bp + ((rb + 32) ^ swzS));
        H2x4 af0, af1;
#pragma unroll
        for (int i = 0; i < 4; ++i) {
          af0.h2[i] = __hmul2(tp01.h2[i], d0.h);
          af1.h2[i] = __hmul2(tp11.h2[i], d1.h);
        }
        acc0 = __builtin_amdgcn_mfma_f32_32x32x16_f16(af0.v, bf, acc0, 0, 0, 0);
        acc1 = __builtin_amdgcn_mfma_f32_32x32x16_f16(af1.v, bf, acc1, 0, 0, 0);
      }
    }
    reduce_T(smem, acc0, acc1, p, kh, h, scol);  // -> T2 then T3
  }

  // ---------- stage D: out = T3 @ last (p==0 waves; rows kh*32..) ----------
  if (p == 0) {
    f32x16 accd;
#pragma unroll
    for (int i = 0; i < 16; ++i) accd[i] = 0.f;
    const unsigned char* lastT = ws + WS_LASTT;
#pragma unroll
    for (int kb = 0; kb < 4; ++kb) {
      const int cb = kb * 32 + h * 16;
      f16x8 bf = *(const f16x8*)(lastT + scol * 128 + cb);
      f16x8 af = *(const f16x8*)(smem + T_OFF + (kh * 32 + l31) * 128 + (cb ^ swzA));
      accd = __builtin_amdgcn_mfma_f32_32x32x16_f16(af, bf, accd, 0, 0, 0);
    }
#pragma unroll
    for (int j = 0; j < 16; ++j) {
      const int r0 = (j & 3) + 8 * (j >> 2) + 4 * h;
      out[(size_t)(bg0 + kh * 32 + r0) * 64 + scol] = accd[j];
    }
  }
}

extern "C" void kernel_launch(void* const* d_in, const int* in_sizes, int n_in,
                              void* d_out, int out_size, void* d_ws, size_t ws_size,
                              hipStream_t stream) {
  const float* x      = (const float*)d_in[0];
  const float* layer0 = (const float*)d_in[1];
  const float* core1  = (const float*)d_in[2];
  const float* core2  = (const float*)d_in[3];
  const float* last   = (const float*)d_in[4];
  const float* lnw    = (const float*)d_in[5];
  const float* lnb    = (const float*)d_in[6];
  unsigned char* ws   = (unsigned char*)d_ws;
  float* outp         = (float*)d_out;

  tt_prep<<<1036, 512, 0, stream>>>(layer0, core1, core2, last, ws);
  tt_fused<<<512, 512, 0, stream>>>(x, lnw, lnb, ws, outp);
}